// Round 12
// baseline (214.706 us; speedup 1.0000x reference)
//
#include <hip/hip_runtime.h>

// ---------------- geometry ----------------
constexpr int HWSZ = 512 * 512;          // 2^18 pixels per plane
constexpr int NPIX = 8 * HWSZ;           // 2,097,152
constexpr float EPS = 1e-5f;
constexpr int ITERS = 8;                 // pixel tiles (32 px) per wave
constexpr int GRID  = 2048;              // 2048 blocks * 4 waves * 8 iters * 32 px = NPIX

// folded fp16 weights, PADDED strides (stride_dw === 2 mod 4 -> 2-way LDS bank
// aliasing = free [m136]; rows 8B-aligned for ds_read_b64). K includes bias col.
constexpr int S1 = 20, S2 = 148, S3 = 84, S4 = 52;   // row strides (f16)
constexpr int OFF_W1 = 0;                 // [128][20]  cols 0-2 w, 3 bias, rest 0
constexpr int OFF_W2 = 2560;              // [64][148]  cols 0-127 w, 128 bias, rest 0
constexpr int OFF_W3 = 12032;             // [32][84]   cols 0-63 w, 64 bias, rest 0
constexpr int OFF_W4 = 14720;             // [32][52]   rows 0-15: cols 0-31 w, 32 bias; rows 16-31 zero
constexpr int F16_TOTAL = 16384;          // exactly 32 KB
constexpr int OFF_WH_F32 = F16_TOTAL / 2; // float index into ws: wh[16]
constexpr int OFF_BH_F32 = OFF_WH_F32 + 16;

typedef _Float16 half8  __attribute__((ext_vector_type(8)));
typedef _Float16 half4  __attribute__((ext_vector_type(4)));
typedef _Float16 half2t __attribute__((ext_vector_type(2)));
typedef float    f32x16 __attribute__((ext_vector_type(16)));
typedef unsigned int uint4t __attribute__((ext_vector_type(4)));

#define MFMA32(a, b, c) __builtin_amdgcn_mfma_f32_32x32x16_f16((a), (b), (c), 0, 0, 0)

// -------------- weight fold/pack kernel (padded layout) --------------
__global__ void fold_weights(
    const float* __restrict__ w1, const float* __restrict__ g1, const float* __restrict__ b1,
    const float* __restrict__ m1, const float* __restrict__ v1,
    const float* __restrict__ w2, const float* __restrict__ g2, const float* __restrict__ b2,
    const float* __restrict__ m2, const float* __restrict__ v2,
    const float* __restrict__ w3, const float* __restrict__ g3, const float* __restrict__ b3,
    const float* __restrict__ m3, const float* __restrict__ v3,
    const float* __restrict__ w4, const float* __restrict__ g4, const float* __restrict__ b4,
    const float* __restrict__ m4, const float* __restrict__ v4,
    const float* __restrict__ wh, const float* __restrict__ bh,
    void* __restrict__ wsv)
{
    _Float16* wsh = (_Float16*)wsv;
    float*    wsf = (float*)wsv;
    int idx = blockIdx.x * 256 + threadIdx.x;

    if (idx < OFF_W2) {                          // W1 [128][20]
        int co = idx / S1, k = idx - co * S1;
        float inv = g1[co] / sqrtf(v1[co] + EPS);
        float val = (k < 3) ? w1[co * 3 + k] * inv
                  : (k == 3) ? (b1[co] - m1[co] * inv) : 0.0f;
        wsh[idx] = (_Float16)val;
    } else if (idx < OFF_W3) {                   // W2 [64][148]
        int i = idx - OFF_W2;
        int co = i / S2, k = i - co * S2;
        float inv = g2[co] / sqrtf(v2[co] + EPS);
        float val = (k < 128) ? w2[co * 128 + k] * inv
                  : (k == 128) ? (b2[co] - m2[co] * inv) : 0.0f;
        wsh[idx] = (_Float16)val;
    } else if (idx < OFF_W4) {                   // W3 [32][84]
        int i = idx - OFF_W3;
        int co = i / S3, k = i - co * S3;
        float inv = g3[co] / sqrtf(v3[co] + EPS);
        float val = (k < 64) ? w3[co * 64 + k] * inv
                  : (k == 64) ? (b3[co] - m3[co] * inv) : 0.0f;
        wsh[idx] = (_Float16)val;
    } else if (idx < F16_TOTAL) {                // W4 [32][52], rows 16-31 zero
        int i = idx - OFF_W4;
        int co = i / S4, k = i - co * S4;
        float val = 0.0f;
        if (co < 16) {
            float inv = g4[co] / sqrtf(v4[co] + EPS);
            val = (k < 32) ? w4[co * 32 + k] * inv
                : (k == 32) ? (b4[co] - m4[co] * inv) : 0.0f;
        }
        wsh[idx] = (_Float16)val;
    } else if (idx < F16_TOTAL + 16) {           // wh (f32)
        wsf[OFF_WH_F32 + (idx - F16_TOTAL)] = wh[idx - F16_TOTAL];
    } else if (idx == F16_TOTAL + 16) {          // bh
        wsf[OFF_BH_F32] = bh[0];
    }
}

// LDS fragment read: two ds_read_b64 (8B-aligned rows), const offsets fold to imm
__device__ inline half8 ldsw(const _Float16* W, int off) {
    half4 lo = *(const half4*)(W + off);
    half4 hi = *(const half4*)(W + off + 4);
    return half8{lo[0], lo[1], lo[2], lo[3], hi[0], hi[1], hi[2], hi[3]};
}

// relu + f16-pack (cvt_pkrtz) + cross-half exchange: one 32-row D tile -> 2 B frags.
// Identical exchange structure to the R9-verified kernel (shfl_xor only).
__device__ inline void repack_tile(const f32x16 d, bool hi, half8* out2) {
    unsigned p[8];
    #pragma unroll
    for (int w = 0; w < 8; ++w) {
        auto t = __builtin_amdgcn_cvt_pkrtz(fmaxf(d[2 * w], 0.0f),
                                            fmaxf(d[2 * w + 1], 0.0f));
        p[w] = __builtin_bit_cast(unsigned, t);   // __fp16x2 -> u32, bit-identical
    }
    #pragma unroll
    for (int ks = 0; ks < 2; ++ks) {
        const int b = 4 * ks;
        unsigned t0 = hi ? p[b + 0] : p[b + 2];
        unsigned t1 = hi ? p[b + 1] : p[b + 3];
        unsigned r0 = (unsigned)__shfl_xor((int)t0, 32, 64);
        unsigned r1 = (unsigned)__shfl_xor((int)t1, 32, 64);
        uint4t f;
        f.x = hi ? r0 : p[b + 0];
        f.y = hi ? r1 : p[b + 1];
        f.z = hi ? p[b + 2] : r0;
        f.w = hi ? p[b + 3] : r1;
        out2[ks] = __builtin_bit_cast(half8, f);
    }
}

__device__ inline f32x16 zero16() {
    f32x16 z;
    #pragma unroll
    for (int i = 0; i < 16; ++i) z[i] = 0.0f;
    return z;
}

// -------------- fused MLP: weights in LDS, all-MFMA layers --------------
__global__ __launch_bounds__(256, 3) void mlp_mfma(
    const float* __restrict__ x, const void* __restrict__ wsv, float* __restrict__ out)
{
    const _Float16* wsh = (const _Float16*)wsv;
    const float*    wsf = (const float*)wsv;

    __shared__ _Float16 WL[F16_TOTAL];   // 32 KB

    const int tid  = threadIdx.x;
    const int l    = tid & 63;
    const int g    = l >> 5;
    const bool hi  = (g != 0);
    const int col  = l & 31;
    const int wave = tid >> 6;
    const int wgid = blockIdx.x * 4 + wave;

    // ---- stage all folded weights to LDS (2048 half8 chunks, 8 rounds) ----
    {
        const half8* gsrc = (const half8*)wsh;
        half8* ldst = (half8*)WL;
        #pragma unroll
        for (int r = 0; r < 8; ++r) ldst[tid + 256 * r] = gsrc[tid + 256 * r];
    }

    // head weights (global, read once)
    float whv[8];
    #pragma unroll
    for (int e = 0; e < 8; ++e)
        whv[e] = wsf[OFF_WH_F32 + ((e & 3) + 8 * (e >> 2) + 4 * g)];
    const float bhv = wsf[OFF_BH_F32];

    __syncthreads();

    // per-lane LDS base offsets (f16 units); fragment selects add const imms
    const int a1a = S1 * col + 8 * g;              // + 640*mt   (32*S1)
    const int a2a = OFF_W2 + S2 * col + 8 * g;     // + 4736*mt + 16*ks  (32*S2)
    const int a3a = OFF_W3 + S3 * col + 8 * g;     // + 16*ks
    const int a4a = OFF_W4 + S4 * col + 8 * g;     // + 16*ks

    // constant B fragment: 1.0 at the bias K-slot (first col of block)
    uint4t bbu; bbu.x = (g == 0) ? 0x00003C00u : 0u; bbu.y = 0u; bbu.z = 0u; bbu.w = 0u;
    const half8 Bbias = __builtin_bit_cast(half8, bbu);

    // ---- pixel addressing: wave owns 256 contiguous pixels in one plane ----
    const int q0 = wgid * (ITERS * 32);            // < 2^21, int ok
    const int n  = q0 >> 18;
    const int p0 = q0 & (HWSZ - 1);
    const float* xp = x + (size_t)n * 3 * HWSZ + p0 + col;
    float* op = out + q0 + col;

    float xc0 = xp[0], xc1 = xp[HWSZ], xc2 = xp[2 * HWSZ];

    for (int it = 0; it < ITERS; ++it) {
        // B1: k = {x0,x1,x2,1(bias),0...}; upper lane-half zero
        half2t t01; t01.x = (_Float16)xc0; t01.y = (_Float16)xc1;
        half2t t23; t23.x = (_Float16)xc2; t23.y = (_Float16)1.0f;
        unsigned bw0 = __builtin_bit_cast(unsigned, t01);
        unsigned bw1 = __builtin_bit_cast(unsigned, t23);
        uint4t b1u; b1u.x = (g == 0) ? bw0 : 0u; b1u.y = (g == 0) ? bw1 : 0u; b1u.z = 0u; b1u.w = 0u;
        const half8 B1 = __builtin_bit_cast(half8, b1u);

        if (it + 1 < ITERS) {            // prefetch next 32 px (overlaps compute)
            xp += 32;
            xc0 = xp[0]; xc1 = xp[HWSZ]; xc2 = xp[2 * HWSZ];
        }

        // ---- L1 (3->128, K=16, bias in K) + repack -> B2 ----
        half8 B2[8];
        #pragma unroll
        for (int h = 0; h < 2; ++h) {
            f32x16 a0 = MFMA32(ldsw(WL, a1a + 640 * (2 * h + 0)), B1, zero16());
            f32x16 a1 = MFMA32(ldsw(WL, a1a + 640 * (2 * h + 1)), B1, zero16());
            repack_tile(a0, hi, &B2[4 * h + 0]);
            repack_tile(a1, hi, &B2[4 * h + 2]);
        }

        // ---- L2 (128->64, K=144 incl bias) ----
        f32x16 c20 = zero16(), c21 = zero16();
        #pragma unroll
        for (int ks = 0; ks < 8; ++ks) {
            c20 = MFMA32(ldsw(WL, a2a + 16 * ks),        B2[ks], c20);
            c21 = MFMA32(ldsw(WL, a2a + 4736 + 16 * ks), B2[ks], c21);
        }
        c20 = MFMA32(ldsw(WL, a2a + 128),        Bbias, c20);
        c21 = MFMA32(ldsw(WL, a2a + 4736 + 128), Bbias, c21);

        // ---- repack -> B3; L3 (64->32, K=80 incl bias) ----
        half8 B3[4];
        repack_tile(c20, hi, &B3[0]);
        repack_tile(c21, hi, &B3[2]);
        f32x16 c3 = zero16();
        #pragma unroll
        for (int ks = 0; ks < 4; ++ks) c3 = MFMA32(ldsw(WL, a3a + 16 * ks), B3[ks], c3);
        c3 = MFMA32(ldsw(WL, a3a + 64), Bbias, c3);

        // ---- repack -> B4; L4 (32->16, K=48 incl bias, M padded) ----
        half8 B4[2];
        repack_tile(c3, hi, &B4[0]);
        f32x16 c4 = zero16();
        c4 = MFMA32(ldsw(WL, a4a +  0), B4[0], c4);
        c4 = MFMA32(ldsw(WL, a4a + 16), B4[1], c4);
        c4 = MFMA32(ldsw(WL, a4a + 32), Bbias, c4);

        // ---- head: out = sum_ch wh[ch]*relu(h4[ch]) + bh ----
        float s = 0.0f;
        #pragma unroll
        for (int e = 0; e < 8; ++e) s = fmaf(whv[e], fmaxf(c4[e], 0.0f), s);
        float partner = __shfl_xor(s, 32, 64);
        float val = s + partner + bhv;
        if (l < 32) op[0] = val;
        op += 32;
    }
}

extern "C" void kernel_launch(void* const* d_in, const int* in_sizes, int n_in,
                              void* d_out, int out_size, void* d_ws, size_t ws_size,
                              hipStream_t stream) {
    const float* x  = (const float*)d_in[0];
    const float* w1 = (const float*)d_in[1];
    const float* g1 = (const float*)d_in[2];
    const float* b1 = (const float*)d_in[3];
    const float* m1 = (const float*)d_in[4];
    const float* v1 = (const float*)d_in[5];
    const float* w2 = (const float*)d_in[6];
    const float* g2 = (const float*)d_in[7];
    const float* b2 = (const float*)d_in[8];
    const float* m2 = (const float*)d_in[9];
    const float* v2 = (const float*)d_in[10];
    const float* w3 = (const float*)d_in[11];
    const float* g3 = (const float*)d_in[12];
    const float* b3 = (const float*)d_in[13];
    const float* m3 = (const float*)d_in[14];
    const float* v3 = (const float*)d_in[15];
    const float* w4 = (const float*)d_in[16];
    const float* g4 = (const float*)d_in[17];
    const float* b4 = (const float*)d_in[18];
    const float* m4 = (const float*)d_in[19];
    const float* v4 = (const float*)d_in[20];
    const float* wh = (const float*)d_in[21];
    const float* bh = (const float*)d_in[22];

    fold_weights<<<65, 256, 0, stream>>>(w1, g1, b1, m1, v1,
                                         w2, g2, b2, m2, v2,
                                         w3, g3, b3, m3, v3,
                                         w4, g4, b4, m4, v4,
                                         wh, bh, d_ws);

    mlp_mfma<<<GRID, 256, 0, stream>>>(x, d_ws, (float*)d_out);
}